// Round 8
// baseline (322.264 us; speedup 1.0000x reference)
//
#include <hip/hip_runtime.h>
#include <hip/hip_bf16.h>

typedef __attribute__((ext_vector_type(8))) short short8;
typedef __attribute__((ext_vector_type(4))) float f32x4;

__device__ inline f32x4 mfma16(short8 a, short8 b, f32x4 c) {
    return __builtin_amdgcn_mfma_f32_16x16x32_bf16(a, b, c, 0, 0, 0);
}
__device__ inline short f2bf(float x) {
    __hip_bfloat16 h = __float2bfloat16(x);
    return *reinterpret_cast<short*>(&h);
}
__device__ inline unsigned short f2bfu(float x) {
    __hip_bfloat16 h = __float2bfloat16(x);
    return *reinterpret_cast<unsigned short*>(&h);
}
__device__ inline float bf2f(short u) {
    __hip_bfloat16 h = *reinterpret_cast<__hip_bfloat16*>(&u);
    return __bfloat162float(h);
}
__device__ inline float scrub(float v, float s) {
    return (fabsf(v) < 1e30f) ? v : s;
}
__device__ inline short8 scaleq(short8 v) {   // fold 1/sqrt(hd)=0.125 into Q (exact in bf16)
    short8 r;
#pragma unroll
    for (int j = 0; j < 8; j++) r[j] = f2bf(bf2f(v[j]) * 0.125f);
    return r;
}
// async global->LDS 16B copy (m97 recipe). Dest MUST be wave-uniform base +
// lane*16 (linear LDS, no padding) -- hence LDK=64 in gemm_bt.
__device__ inline void gload_lds16(const short* g, short* l) {
    __builtin_amdgcn_global_load_lds(
        (const __attribute__((address_space(1))) unsigned int*)g,
        (__attribute__((address_space(3))) unsigned int*)l,
        16, 0, 0);
}

// ---- dtype detection ----
__global__ void detect_dtype(const unsigned short* __restrict__ x, int* flag) {
    __shared__ int cnt;
    if (threadIdx.x == 0) cnt = 0;
    __syncthreads();
    int c = 0;
    for (int i = threadIdx.x; i < 1024; i += 256) {
        unsigned short u = x[i];
        int e = (u >> 7) & 0xFF;
        if ((u & 0x7FFF) == 0 || (e >= 110 && e <= 143)) c++;
    }
    atomicAdd(&cnt, c);
    __syncthreads();
    if (threadIdx.x == 0) flag[0] = (cnt < 819) ? 1 : 0;
}

__global__ void conv_bias(const void* __restrict__ in, short* __restrict__ out,
                          int n, const int* __restrict__ flag) {
    int i = blockIdx.x * 256 + threadIdx.x;
    if (i >= n) return;
    out[i] = (*flag) ? f2bf(((const float*)in)[i]) : ((const short*)in)[i];
}

__global__ __launch_bounds__(256) void conv_x(const void* __restrict__ in,
                                              short* __restrict__ out, int n,
                                              const int* __restrict__ flag) {
    int i = (blockIdx.x * 256 + threadIdx.x) * 4;
    if (i >= n) return;
    if (*flag) {
        float4 f = *(const float4*)((const float*)in + i);
        unsigned int u0 = ((unsigned int)f2bfu(f.y) << 16) | f2bfu(f.x);
        unsigned int u1 = ((unsigned int)f2bfu(f.w) << 16) | f2bfu(f.z);
        *(uint2*)(out + i) = make_uint2(u0, u1);
    } else {
        *(uint2*)(out + i) = *(const uint2*)((const short*)in + i);
    }
}

__global__ void fill_sentinel(void* out, int n, const int* __restrict__ flag) {
    int i = blockIdx.x * 256 + threadIdx.x;
    if (i >= n) return;
    if (*flag) ((float*)out)[i] = 3e5f; else ((short*)out)[i] = f2bf(3e5f);
}

// ---- transpose (poly input) ----
__global__ __launch_bounds__(256) void transpose_poly(const void* __restrict__ in,
                                                      short* __restrict__ out,
                                                      int R, int C,
                                                      const int* __restrict__ flag) {
    __shared__ short tile[32][33];
    const bool f32 = (*flag) != 0;
    int tx = threadIdx.x & 31, ty = threadIdx.x >> 5;
    int r0 = blockIdx.y * 32, c0 = blockIdx.x * 32;
#pragma unroll
    for (int i = 0; i < 4; i++) {
        size_t off = (size_t)(r0 + ty + i * 8) * C + c0 + tx;
        tile[ty + i * 8][tx] = f32 ? f2bf(((const float*)in)[off]) : ((const short*)in)[off];
    }
    __syncthreads();
#pragma unroll
    for (int i = 0; i < 4; i++)
        out[(size_t)(c0 + ty + i * 8) * R + r0 + tx] = tile[tx][ty + i * 8];
}

// ---- GEMM: m97-style async staging -----------------------------------------
// Staging via __builtin_amdgcn_global_load_lds width=16 (the compiler never
// auto-emits it): removes the VGPR round-trip + address VALU of the short8
// staging loop. Ladder evidence: m93 517 TF -> m97 874 TF (+69%), same
// 128^2 tile / 4x4 acc / ds_read_b128 pattern. LDS is LINEAR [128][64]
// (LDK=64): global_load_lds writes base+lane*16, padding would corrupt.
// Dest check: idx = p*2048 + tid*8 shorts -> byte off = p*4096 + wave*1024
// + lane*16 = wave-uniform + lane*16. __syncthreads() drains vmcnt(0)
// (compiler-emitted before s_barrier).
#define LDK 64

__global__ __launch_bounds__(256) void gemm_bt(const short* __restrict__ A,
                                               const short* __restrict__ Bt,
                                               const short* __restrict__ bias,
                                               void* __restrict__ Cv,
                                               int N, int K,
                                               const int* __restrict__ flag,
                                               int c_poly, float sent) {
    alignas(16) __shared__ short As[128 * LDK];
    alignas(16) __shared__ short Bs[128 * LDK];
    const bool cf32 = c_poly && (*flag);
    int tid = threadIdx.x;
    int wave = tid >> 6, lane = tid & 63;
    int lrow = lane & 15, lq = lane >> 4;
    int wm = (wave >> 1) * 64, wn = (wave & 1) * 64;
    int m0 = blockIdx.y * 128, n0 = blockIdx.x * 128;

    f32x4 acc[4][4];
#pragma unroll
    for (int i = 0; i < 4; i++)
#pragma unroll
        for (int j = 0; j < 4; j++) acc[i][j] = (f32x4){0.f, 0.f, 0.f, 0.f};

    for (int kb = 0; kb < K; kb += 64) {
#pragma unroll
        for (int p = 0; p < 4; p++) {
            int idx = p * 2048 + tid * 8;      // short index into [128][64] tile
            int row = idx >> 6;
            int col = idx & 63;
            gload_lds16(&A[(size_t)(m0 + row) * K + kb + col], &As[idx]);
            gload_lds16(&Bt[(size_t)(n0 + row) * K + kb + col], &Bs[idx]);
        }
        __syncthreads();
#pragma unroll
        for (int ks = 0; ks < 2; ks++) {
            short8 af[4], bf[4];
#pragma unroll
            for (int i = 0; i < 4; i++)
                af[i] = *(short8*)&As[(wm + i * 16 + lrow) * LDK + ks * 32 + lq * 8];
#pragma unroll
            for (int i = 0; i < 4; i++)
                bf[i] = *(short8*)&Bs[(wn + i * 16 + lrow) * LDK + ks * 32 + lq * 8];
#pragma unroll
            for (int i = 0; i < 4; i++)
#pragma unroll
                for (int j = 0; j < 4; j++)
                    acc[i][j] = mfma16(af[i], bf[j], acc[i][j]);
        }
        __syncthreads();
    }

    const __hip_bfloat16* bias16 = (const __hip_bfloat16*)bias;
#pragma unroll
    for (int j = 0; j < 4; j++) {
        int col = n0 + wn + j * 16 + lrow;
        float bv = __bfloat162float(bias16[col]);
#pragma unroll
        for (int i = 0; i < 4; i++) {
            int rbase = m0 + wm + i * 16 + lq * 4;
#pragma unroll
            for (int r = 0; r < 4; r++) {
                float val = scrub(acc[i][j][r] + bv, sent);
                size_t off = (size_t)(rbase + r) * N + col;
                if (cf32) ((float*)Cv)[off] = val; else ((short*)Cv)[off] = f2bf(val);
            }
        }
    }
}

// ---- flash attention: R0 structure + software pipeline (unchanged from R7) -
// R7 verified: register prefetch of iter+1's K/V cut 124 -> 105 us (VGPR 100,
// zero spill). Kept byte-identical this round; GEMM is now the larger cost.
#define VP2 72
#define PP 72

__global__ __launch_bounds__(256, 2) void attn_kernel(const short* __restrict__ QKV,
                                                      short* __restrict__ AO,
                                                      const int* __restrict__ maskp) {
    constexpr int S = 2048, C3 = 3072;
    alignas(16) __shared__ short Vt[2][64 * VP2];
    alignas(16) __shared__ short Pt[4][2][16 * PP];

    int tid = threadIdx.x;
    int wave = tid >> 6, lane = tid & 63;
    int lrow = lane & 15, lq = lane >> 4;
    int bh = blockIdx.y;
    const bool causal = (*maskp) != 0;
    const short* base = QKV + (size_t)(bh >> 4) * S * C3 + (bh & 15) * 192;

    int vi2 = (tid & 31) * 2;     // kv pair base for V staging
    int vd0 = (tid >> 5) * 8;     // 8 d per thread

    int buf = 0;
    for (int tile = 0; tile < 2; tile++) {
        int q0t = (tile == 0) ? blockIdx.x * 128 : 1920 - blockIdx.x * 128;

        int qg[2];
        short8 qf0[2], qf1[2];
#pragma unroll
        for (int g = 0; g < 2; g++) {
            qg[g] = q0t + wave * 32 + g * 16 + lrow;
            qf0[g] = scaleq(*(const short8*)(base + (size_t)qg[g] * C3 + lq * 8));
            qf1[g] = scaleq(*(const short8*)(base + (size_t)qg[g] * C3 + 32 + lq * 8));
        }

        float m_i[2] = {-1e38f, -1e38f}, l_i[2] = {0.f, 0.f};
        f32x4 acc[2][4];
#pragma unroll
        for (int g = 0; g < 2; g++)
#pragma unroll
            for (int nt = 0; nt < 4; nt++) acc[g][nt] = (f32x4){0.f, 0.f, 0.f, 0.f};

        int nkv = causal ? (q0t + 128) : S;

        // ---- prologue: prefetch V + K for kv0 = 0 into registers ----
        short8 va, vb, kf0[4], kf1[4];
        {
            const short* vs0 = base + (size_t)vi2 * C3 + 128 + vd0;
            va = *(const short8*)vs0;
            vb = *(const short8*)(vs0 + C3);
#pragma unroll
            for (int sub = 0; sub < 4; sub++) {
                const short* kb = base + (size_t)(sub * 16 + lrow) * C3 + 64;
                kf0[sub] = *(const short8*)(kb + lq * 8);
                kf1[sub] = *(const short8*)(kb + 32 + lq * 8);
            }
        }

        for (int kv0 = 0; kv0 < nkv; kv0 += 64) {
            // ---- write pre-staged V^T (64 kv x 64 d) into LDS ----
            {
                union { short8 v; unsigned short u[8]; } a, b;
                a.v = va; b.v = vb;
                unsigned int* vt = (unsigned int*)&Vt[buf][0];
#pragma unroll
                for (int j = 0; j < 8; j++)
                    vt[((vd0 + j) * VP2 + vi2) >> 1] =
                        ((unsigned int)b.u[j] << 16) | a.u[j];
            }
            __syncthreads();

            // ---- issue next-iter global loads early (clamped on last) ----
            int kvn = (kv0 + 64 < nkv) ? kv0 + 64 : kv0;
            short8 va_n, vb_n, kf0_n[4], kf1_n[4];
            {
                const short* vs0 = base + (size_t)(kvn + vi2) * C3 + 128 + vd0;
                va_n = *(const short8*)vs0;
                vb_n = *(const short8*)(vs0 + C3);
#pragma unroll
                for (int sub = 0; sub < 4; sub++) {
                    const short* kb = base + (size_t)(kvn + sub * 16 + lrow) * C3 + 64;
                    kf0_n[sub] = *(const short8*)(kb + lq * 8);
                    kf1_n[sub] = *(const short8*)(kb + 32 + lq * 8);
                }
            }

            // ---- S^T for both groups using pre-loaded K ----
            f32x4 s[2][4];
#pragma unroll
            for (int sub = 0; sub < 4; sub++) {
#pragma unroll
                for (int g = 0; g < 2; g++) {
                    f32x4 a = (f32x4){0.f, 0.f, 0.f, 0.f};
                    a = mfma16(kf0[sub], qf0[g], a);
                    a = mfma16(kf1[sub], qf1[g], a);
                    s[g][sub] = a;
                }
            }

            // ---- per-group: mask, online softmax (defer-max), pack P ----
#pragma unroll
            for (int g = 0; g < 2; g++) {
                if (causal && (kv0 + 63 > q0t + wave * 32 + g * 16)) {
#pragma unroll
                    for (int sub = 0; sub < 4; sub++) {
                        int kvg = kv0 + sub * 16 + lq * 4;
#pragma unroll
                        for (int rr = 0; rr < 4; rr++)
                            if (kvg + rr > qg[g]) s[g][sub][rr] = -1e30f;
                    }
                }
                float vmax = -1e38f;
#pragma unroll
                for (int sub = 0; sub < 4; sub++) {
                    float a = fmaxf(fmaxf(s[g][sub][0], s[g][sub][1]),
                                    fmaxf(s[g][sub][2], s[g][sub][3]));
                    vmax = fmaxf(vmax, a);
                }
                vmax = fmaxf(vmax, __shfl_xor(vmax, 16, 64));
                vmax = fmaxf(vmax, __shfl_xor(vmax, 32, 64));
                float mnew = m_i[g];
                // defer-max: only rescale when some row's max grew past m+8
                if (!__all(vmax <= m_i[g] + 8.0f)) {
                    mnew = fmaxf(m_i[g], vmax);
                    float alpha = __expf(m_i[g] - mnew);
                    l_i[g] *= alpha;
#pragma unroll
                    for (int nt = 0; nt < 4; nt++)
#pragma unroll
                        for (int rr = 0; rr < 4; rr++) acc[g][nt][rr] *= alpha;
                }
                float lsum = 0.f;
                unsigned int pk[4][2];
#pragma unroll
                for (int sub = 0; sub < 4; sub++) {
                    float p0 = __expf(s[g][sub][0] - mnew);
                    float p1 = __expf(s[g][sub][1] - mnew);
                    float p2 = __expf(s[g][sub][2] - mnew);
                    float p3 = __expf(s[g][sub][3] - mnew);
                    lsum += (p0 + p1) + (p2 + p3);
                    pk[sub][0] = ((unsigned int)f2bfu(p1) << 16) | f2bfu(p0);
                    pk[sub][1] = ((unsigned int)f2bfu(p3) << 16) | f2bfu(p2);
                }
                lsum += __shfl_xor(lsum, 16, 64);
                lsum += __shfl_xor(lsum, 32, 64);
                l_i[g] += lsum;
                m_i[g] = mnew;
                // P[q=lrow][kv=sub*16+lq*4 .. +3] : 4 x ds_write_b64
                unsigned int* pt = (unsigned int*)&Pt[wave][g][0];
#pragma unroll
                for (int sub = 0; sub < 4; sub++)
                    *(uint2*)&pt[(lrow * PP + sub * 16 + lq * 4) >> 1] =
                        make_uint2(pk[sub][0], pk[sub][1]);
            }

            // ---- PV: O^T += V^T · P^T, vf shared across groups ----
#pragma unroll
            for (int ks = 0; ks < 2; ks++) {
                short8 pfA = *(short8*)&Pt[wave][0][lrow * PP + ks * 32 + lq * 8];
                short8 pfB = *(short8*)&Pt[wave][1][lrow * PP + ks * 32 + lq * 8];
#pragma unroll
                for (int nt = 0; nt < 4; nt++) {
                    short8 vf = *(short8*)&Vt[buf][(nt * 16 + lrow) * VP2 + ks * 32 + lq * 8];
                    acc[0][nt] = mfma16(vf, pfA, acc[0][nt]);
                    acc[1][nt] = mfma16(vf, pfB, acc[1][nt]);
                }
            }

            // ---- rotate prefetched registers ----
            va = va_n; vb = vb_n;
#pragma unroll
            for (int sub = 0; sub < 4; sub++) {
                kf0[sub] = kf0_n[sub];
                kf1[sub] = kf1_n[sub];
            }
            buf ^= 1;
        }

        // ---- epilogue ----
#pragma unroll
        for (int g = 0; g < 2; g++) {
            float inv = 1.f / l_i[g];
            short* ob = AO + ((size_t)bh * S + qg[g]) * 64;
#pragma unroll
            for (int nt = 0; nt < 4; nt++) {
                unsigned int u0 = ((unsigned int)f2bfu(scrub(acc[g][nt][1] * inv, 4e4f)) << 16) |
                                  f2bfu(scrub(acc[g][nt][0] * inv, 4e4f));
                unsigned int u1 = ((unsigned int)f2bfu(scrub(acc[g][nt][3] * inv, 4e4f)) << 16) |
                                  f2bfu(scrub(acc[g][nt][2] * inv, 4e4f));
                *(uint2*)(ob + nt * 16 + lq * 4) = make_uint2(u0, u1);
            }
        }
    }
}

// ---- launch ----
extern "C" void kernel_launch(void* const* d_in, const int* in_sizes, int n_in,
                              void* d_out, int out_size, void* d_ws, size_t ws_size,
                              hipStream_t stream) {
    char* ws = (char*)d_ws;
    int*   flag  = (int*)ws;
    short* bq_bf = (short*)(ws + 65536);
    short* bo_bf = (short*)(ws + 131072);
    short* WqkvT = (short*)(ws + (1ull << 20));
    short* WoutT = (short*)(ws + 7ull * (1ull << 20));
    short* xbfAO = (short*)(ws + 9ull * (1ull << 20));   // x_bf, later AO
    short* QKVc  = (short*)(ws + 25ull * (1ull << 20));

    detect_dtype<<<1, 256, 0, stream>>>((const unsigned short*)d_in[0], flag);

    if (ws_size < 73ull * 1048576) {
        fill_sentinel<<<(8388608 + 255) / 256, 256, 0, stream>>>(d_out, 8388608, flag);
        return;
    }

    conv_bias<<<12, 256, 0, stream>>>(d_in[2], bq_bf, 3072, flag);
    conv_bias<<<4, 256, 0, stream>>>(d_in[4], bo_bf, 1024, flag);
    transpose_poly<<<dim3(96, 32), 256, 0, stream>>>(d_in[1], WqkvT, 1024, 3072, flag);
    transpose_poly<<<dim3(32, 32), 256, 0, stream>>>(d_in[3], WoutT, 1024, 1024, flag);
    conv_x<<<8192, 256, 0, stream>>>(d_in[0], xbfAO, 8388608, flag);

    gemm_bt<<<dim3(24, 64), 256, 0, stream>>>(xbfAO, WqkvT, bq_bf, QKVc,
                                              3072, 1024, flag, 0, 8e4f);
    attn_kernel<<<dim3(8, 64), 256, 0, stream>>>(QKVc, xbfAO, (const int*)d_in[5]);
    gemm_bt<<<dim3(8, 64), 256, 0, stream>>>(xbfAO, WoutT, bo_bf, d_out,
                                             1024, 1024, flag, 1, 2e4f);
}

// Round 9
// 304.668 us; speedup vs baseline: 1.0578x; 1.0578x over previous
//
#include <hip/hip_runtime.h>
#include <hip/hip_bf16.h>

typedef __attribute__((ext_vector_type(8))) short short8;
typedef __attribute__((ext_vector_type(4))) float f32x4;

__device__ inline f32x4 mfma16(short8 a, short8 b, f32x4 c) {
    return __builtin_amdgcn_mfma_f32_16x16x32_bf16(a, b, c, 0, 0, 0);
}
__device__ inline short f2bf(float x) {
    __hip_bfloat16 h = __float2bfloat16(x);
    return *reinterpret_cast<short*>(&h);
}
__device__ inline unsigned short f2bfu(float x) {
    __hip_bfloat16 h = __float2bfloat16(x);
    return *reinterpret_cast<unsigned short*>(&h);
}
__device__ inline float bf2f(short u) {
    __hip_bfloat16 h = *reinterpret_cast<__hip_bfloat16*>(&u);
    return __bfloat162float(h);
}
__device__ inline float scrub(float v, float s) {
    return (fabsf(v) < 1e30f) ? v : s;
}
__device__ inline short8 scaleq(short8 v) {   // fold 1/sqrt(hd)=0.125 into Q (exact in bf16)
    short8 r;
#pragma unroll
    for (int j = 0; j < 8; j++) r[j] = f2bf(bf2f(v[j]) * 0.125f);
    return r;
}

// ---- dtype detection ----
__global__ void detect_dtype(const unsigned short* __restrict__ x, int* flag) {
    __shared__ int cnt;
    if (threadIdx.x == 0) cnt = 0;
    __syncthreads();
    int c = 0;
    for (int i = threadIdx.x; i < 1024; i += 256) {
        unsigned short u = x[i];
        int e = (u >> 7) & 0xFF;
        if ((u & 0x7FFF) == 0 || (e >= 110 && e <= 143)) c++;
    }
    atomicAdd(&cnt, c);
    __syncthreads();
    if (threadIdx.x == 0) flag[0] = (cnt < 819) ? 1 : 0;
}

__global__ void conv_bias(const void* __restrict__ in, short* __restrict__ out,
                          int n, const int* __restrict__ flag) {
    int i = blockIdx.x * 256 + threadIdx.x;
    if (i >= n) return;
    out[i] = (*flag) ? f2bf(((const float*)in)[i]) : ((const short*)in)[i];
}

__global__ __launch_bounds__(256) void conv_x(const void* __restrict__ in,
                                              short* __restrict__ out, int n,
                                              const int* __restrict__ flag) {
    int i = (blockIdx.x * 256 + threadIdx.x) * 4;
    if (i >= n) return;
    if (*flag) {
        float4 f = *(const float4*)((const float*)in + i);
        unsigned int u0 = ((unsigned int)f2bfu(f.y) << 16) | f2bfu(f.x);
        unsigned int u1 = ((unsigned int)f2bfu(f.w) << 16) | f2bfu(f.z);
        *(uint2*)(out + i) = make_uint2(u0, u1);
    } else {
        *(uint2*)(out + i) = *(const uint2*)((const short*)in + i);
    }
}

__global__ void fill_sentinel(void* out, int n, const int* __restrict__ flag) {
    int i = blockIdx.x * 256 + threadIdx.x;
    if (i >= n) return;
    if (*flag) ((float*)out)[i] = 3e5f; else ((short*)out)[i] = f2bf(3e5f);
}

// ---- transpose (poly input) ----
__global__ __launch_bounds__(256) void transpose_poly(const void* __restrict__ in,
                                                      short* __restrict__ out,
                                                      int R, int C,
                                                      const int* __restrict__ flag) {
    __shared__ short tile[32][33];
    const bool f32 = (*flag) != 0;
    int tx = threadIdx.x & 31, ty = threadIdx.x >> 5;
    int r0 = blockIdx.y * 32, c0 = blockIdx.x * 32;
#pragma unroll
    for (int i = 0; i < 4; i++) {
        size_t off = (size_t)(r0 + ty + i * 8) * C + c0 + tx;
        tile[ty + i * 8][tx] = f32 ? f2bf(((const float*)in)[off]) : ((const short*)in)[off];
    }
    __syncthreads();
#pragma unroll
    for (int i = 0; i < 4; i++)
        out[(size_t)(c0 + ty + i * 8) * R + r0 + tx] = tile[tx][ty + i * 8];
}

// ---- GEMM: R7 staging + register prefetch pipeline (T14) -------------------
// R8 lesson: global_load_lds forced LDK=64 -> stride-128B ds_read puts all 16
// lrow lanes on one 4-bank group (16-way conflict); async gain ~= conflict
// loss -> neutral. Reverted to LDK=72 (stride 144B = +4 banks/row, conflict-
// free) and instead hid the staging-load latency with the pattern R7 proved
// on attn: prologue-load K-tile 0 into regs; per iter {ds_write staged regs;
// barrier; issue next-tile global loads (first use = NEXT iter's ds_write,
// so latency hides under this iter's 16 MFMA + 8 ds_read); compute; barrier}.
// Same 2 barriers/iter as before -- only the load-issue point moves.
// Last-iter prefetch clamps to kb (reload, discarded) -- no OOB.
#define LDK 72

__global__ __launch_bounds__(256) void gemm_bt(const short* __restrict__ A,
                                               const short* __restrict__ Bt,
                                               const short* __restrict__ bias,
                                               void* __restrict__ Cv,
                                               int N, int K,
                                               const int* __restrict__ flag,
                                               int c_poly, float sent) {
    alignas(16) __shared__ short As[128 * LDK];
    alignas(16) __shared__ short Bs[128 * LDK];
    const bool cf32 = c_poly && (*flag);
    int tid = threadIdx.x;
    int wave = tid >> 6, lane = tid & 63;
    int lrow = lane & 15, lq = lane >> 4;
    int wm = (wave >> 1) * 64, wn = (wave & 1) * 64;
    int m0 = blockIdx.y * 128, n0 = blockIdx.x * 128;

    f32x4 acc[4][4];
#pragma unroll
    for (int i = 0; i < 4; i++)
#pragma unroll
        for (int j = 0; j < 4; j++) acc[i][j] = (f32x4){0.f, 0.f, 0.f, 0.f};

    int srow = tid >> 3;          // 0..31
    int scol = (tid & 7) * 8;     // 0..56 step 8

    // ---- prologue: load K-tile 0 into registers ----
    short8 ar[4], br[4];
#pragma unroll
    for (int p = 0; p < 4; p++) {
        int row = p * 32 + srow;
        ar[p] = *(const short8*)&A[(size_t)(m0 + row) * K + scol];
        br[p] = *(const short8*)&Bt[(size_t)(n0 + row) * K + scol];
    }

    for (int kb = 0; kb < K; kb += 64) {
        // ---- write staged registers to LDS ----
#pragma unroll
        for (int p = 0; p < 4; p++) {
            int row = p * 32 + srow;
            *(short8*)&As[row * LDK + scol] = ar[p];
            *(short8*)&Bs[row * LDK + scol] = br[p];
        }
        __syncthreads();

        // ---- issue next K-tile loads (consumed next iter; clamped last) ----
        int kn = (kb + 64 < K) ? kb + 64 : kb;
#pragma unroll
        for (int p = 0; p < 4; p++) {
            int row = p * 32 + srow;
            ar[p] = *(const short8*)&A[(size_t)(m0 + row) * K + kn + scol];
            br[p] = *(const short8*)&Bt[(size_t)(n0 + row) * K + kn + scol];
        }

        // ---- compute from LDS ----
#pragma unroll
        for (int ks = 0; ks < 2; ks++) {
            short8 af[4], bf[4];
#pragma unroll
            for (int i = 0; i < 4; i++)
                af[i] = *(short8*)&As[(wm + i * 16 + lrow) * LDK + ks * 32 + lq * 8];
#pragma unroll
            for (int i = 0; i < 4; i++)
                bf[i] = *(short8*)&Bs[(wn + i * 16 + lrow) * LDK + ks * 32 + lq * 8];
#pragma unroll
            for (int i = 0; i < 4; i++)
#pragma unroll
                for (int j = 0; j < 4; j++)
                    acc[i][j] = mfma16(af[i], bf[j], acc[i][j]);
        }
        __syncthreads();
    }

    const __hip_bfloat16* bias16 = (const __hip_bfloat16*)bias;
#pragma unroll
    for (int j = 0; j < 4; j++) {
        int col = n0 + wn + j * 16 + lrow;
        float bv = __bfloat162float(bias16[col]);
#pragma unroll
        for (int i = 0; i < 4; i++) {
            int rbase = m0 + wm + i * 16 + lq * 4;
#pragma unroll
            for (int r = 0; r < 4; r++) {
                float val = scrub(acc[i][j][r] + bv, sent);
                size_t off = (size_t)(rbase + r) * N + col;
                if (cf32) ((float*)Cv)[off] = val; else ((short*)Cv)[off] = f2bf(val);
            }
        }
    }
}

// ---- flash attention: R0 structure + software pipeline (unchanged from R7) -
// R7 verified: register prefetch of iter+1's K/V cut 124 -> 105 us (VGPR 100,
// zero spill). Byte-identical since R7.
#define VP2 72
#define PP 72

__global__ __launch_bounds__(256, 2) void attn_kernel(const short* __restrict__ QKV,
                                                      short* __restrict__ AO,
                                                      const int* __restrict__ maskp) {
    constexpr int S = 2048, C3 = 3072;
    alignas(16) __shared__ short Vt[2][64 * VP2];
    alignas(16) __shared__ short Pt[4][2][16 * PP];

    int tid = threadIdx.x;
    int wave = tid >> 6, lane = tid & 63;
    int lrow = lane & 15, lq = lane >> 4;
    int bh = blockIdx.y;
    const bool causal = (*maskp) != 0;
    const short* base = QKV + (size_t)(bh >> 4) * S * C3 + (bh & 15) * 192;

    int vi2 = (tid & 31) * 2;     // kv pair base for V staging
    int vd0 = (tid >> 5) * 8;     // 8 d per thread

    int buf = 0;
    for (int tile = 0; tile < 2; tile++) {
        int q0t = (tile == 0) ? blockIdx.x * 128 : 1920 - blockIdx.x * 128;

        int qg[2];
        short8 qf0[2], qf1[2];
#pragma unroll
        for (int g = 0; g < 2; g++) {
            qg[g] = q0t + wave * 32 + g * 16 + lrow;
            qf0[g] = scaleq(*(const short8*)(base + (size_t)qg[g] * C3 + lq * 8));
            qf1[g] = scaleq(*(const short8*)(base + (size_t)qg[g] * C3 + 32 + lq * 8));
        }

        float m_i[2] = {-1e38f, -1e38f}, l_i[2] = {0.f, 0.f};
        f32x4 acc[2][4];
#pragma unroll
        for (int g = 0; g < 2; g++)
#pragma unroll
            for (int nt = 0; nt < 4; nt++) acc[g][nt] = (f32x4){0.f, 0.f, 0.f, 0.f};

        int nkv = causal ? (q0t + 128) : S;

        // ---- prologue: prefetch V + K for kv0 = 0 into registers ----
        short8 va, vb, kf0[4], kf1[4];
        {
            const short* vs0 = base + (size_t)vi2 * C3 + 128 + vd0;
            va = *(const short8*)vs0;
            vb = *(const short8*)(vs0 + C3);
#pragma unroll
            for (int sub = 0; sub < 4; sub++) {
                const short* kb = base + (size_t)(sub * 16 + lrow) * C3 + 64;
                kf0[sub] = *(const short8*)(kb + lq * 8);
                kf1[sub] = *(const short8*)(kb + 32 + lq * 8);
            }
        }

        for (int kv0 = 0; kv0 < nkv; kv0 += 64) {
            // ---- write pre-staged V^T (64 kv x 64 d) into LDS ----
            {
                union { short8 v; unsigned short u[8]; } a, b;
                a.v = va; b.v = vb;
                unsigned int* vt = (unsigned int*)&Vt[buf][0];
#pragma unroll
                for (int j = 0; j < 8; j++)
                    vt[((vd0 + j) * VP2 + vi2) >> 1] =
                        ((unsigned int)b.u[j] << 16) | a.u[j];
            }
            __syncthreads();

            // ---- issue next-iter global loads early (clamped on last) ----
            int kvn = (kv0 + 64 < nkv) ? kv0 + 64 : kv0;
            short8 va_n, vb_n, kf0_n[4], kf1_n[4];
            {
                const short* vs0 = base + (size_t)(kvn + vi2) * C3 + 128 + vd0;
                va_n = *(const short8*)vs0;
                vb_n = *(const short8*)(vs0 + C3);
#pragma unroll
                for (int sub = 0; sub < 4; sub++) {
                    const short* kb = base + (size_t)(kvn + sub * 16 + lrow) * C3 + 64;
                    kf0_n[sub] = *(const short8*)(kb + lq * 8);
                    kf1_n[sub] = *(const short8*)(kb + 32 + lq * 8);
                }
            }

            // ---- S^T for both groups using pre-loaded K ----
            f32x4 s[2][4];
#pragma unroll
            for (int sub = 0; sub < 4; sub++) {
#pragma unroll
                for (int g = 0; g < 2; g++) {
                    f32x4 a = (f32x4){0.f, 0.f, 0.f, 0.f};
                    a = mfma16(kf0[sub], qf0[g], a);
                    a = mfma16(kf1[sub], qf1[g], a);
                    s[g][sub] = a;
                }
            }

            // ---- per-group: mask, online softmax (defer-max), pack P ----
#pragma unroll
            for (int g = 0; g < 2; g++) {
                if (causal && (kv0 + 63 > q0t + wave * 32 + g * 16)) {
#pragma unroll
                    for (int sub = 0; sub < 4; sub++) {
                        int kvg = kv0 + sub * 16 + lq * 4;
#pragma unroll
                        for (int rr = 0; rr < 4; rr++)
                            if (kvg + rr > qg[g]) s[g][sub][rr] = -1e30f;
                    }
                }
                float vmax = -1e38f;
#pragma unroll
                for (int sub = 0; sub < 4; sub++) {
                    float a = fmaxf(fmaxf(s[g][sub][0], s[g][sub][1]),
                                    fmaxf(s[g][sub][2], s[g][sub][3]));
                    vmax = fmaxf(vmax, a);
                }
                vmax = fmaxf(vmax, __shfl_xor(vmax, 16, 64));
                vmax = fmaxf(vmax, __shfl_xor(vmax, 32, 64));
                float mnew = m_i[g];
                // defer-max: only rescale when some row's max grew past m+8
                if (!__all(vmax <= m_i[g] + 8.0f)) {
                    mnew = fmaxf(m_i[g], vmax);
                    float alpha = __expf(m_i[g] - mnew);
                    l_i[g] *= alpha;
#pragma unroll
                    for (int nt = 0; nt < 4; nt++)
#pragma unroll
                        for (int rr = 0; rr < 4; rr++) acc[g][nt][rr] *= alpha;
                }
                float lsum = 0.f;
                unsigned int pk[4][2];
#pragma unroll
                for (int sub = 0; sub < 4; sub++) {
                    float p0 = __expf(s[g][sub][0] - mnew);
                    float p1 = __expf(s[g][sub][1] - mnew);
                    float p2 = __expf(s[g][sub][2] - mnew);
                    float p3 = __expf(s[g][sub][3] - mnew);
                    lsum += (p0 + p1) + (p2 + p3);
                    pk[sub][0] = ((unsigned int)f2bfu(p1) << 16) | f2bfu(p0);
                    pk[sub][1] = ((unsigned int)f2bfu(p3) << 16) | f2bfu(p2);
                }
                lsum += __shfl_xor(lsum, 16, 64);
                lsum += __shfl_xor(lsum, 32, 64);
                l_i[g] += lsum;
                m_i[g] = mnew;
                // P[q=lrow][kv=sub*16+lq*4 .. +3] : 4 x ds_write_b64
                unsigned int* pt = (unsigned int*)&Pt[wave][g][0];
#pragma unroll
                for (int sub = 0; sub < 4; sub++)
                    *(uint2*)&pt[(lrow * PP + sub * 16 + lq * 4) >> 1] =
                        make_uint2(pk[sub][0], pk[sub][1]);
            }

            // ---- PV: O^T += V^T · P^T, vf shared across groups ----
#pragma unroll
            for (int ks = 0; ks < 2; ks++) {
                short8 pfA = *(short8*)&Pt[wave][0][lrow * PP + ks * 32 + lq * 8];
                short8 pfB = *(short8*)&Pt[wave][1][lrow * PP + ks * 32 + lq * 8];
#pragma unroll
                for (int nt = 0; nt < 4; nt++) {
                    short8 vf = *(short8*)&Vt[buf][(nt * 16 + lrow) * VP2 + ks * 32 + lq * 8];
                    acc[0][nt] = mfma16(vf, pfA, acc[0][nt]);
                    acc[1][nt] = mfma16(vf, pfB, acc[1][nt]);
                }
            }

            // ---- rotate prefetched registers ----
            va = va_n; vb = vb_n;
#pragma unroll
            for (int sub = 0; sub < 4; sub++) {
                kf0[sub] = kf0_n[sub];
                kf1[sub] = kf1_n[sub];
            }
            buf ^= 1;
        }

        // ---- epilogue ----
#pragma unroll
        for (int g = 0; g < 2; g++) {
            float inv = 1.f / l_i[g];
            short* ob = AO + ((size_t)bh * S + qg[g]) * 64;
#pragma unroll
            for (int nt = 0; nt < 4; nt++) {
                unsigned int u0 = ((unsigned int)f2bfu(scrub(acc[g][nt][1] * inv, 4e4f)) << 16) |
                                  f2bfu(scrub(acc[g][nt][0] * inv, 4e4f));
                unsigned int u1 = ((unsigned int)f2bfu(scrub(acc[g][nt][3] * inv, 4e4f)) << 16) |
                                  f2bfu(scrub(acc[g][nt][2] * inv, 4e4f));
                *(uint2*)(ob + nt * 16 + lq * 4) = make_uint2(u0, u1);
            }
        }
    }
}

// ---- launch ----
extern "C" void kernel_launch(void* const* d_in, const int* in_sizes, int n_in,
                              void* d_out, int out_size, void* d_ws, size_t ws_size,
                              hipStream_t stream) {
    char* ws = (char*)d_ws;
    int*   flag  = (int*)ws;
    short* bq_bf = (short*)(ws + 65536);
    short* bo_bf = (short*)(ws + 131072);
    short* WqkvT = (short*)(ws + (1ull << 20));
    short* WoutT = (short*)(ws + 7ull * (1ull << 20));
    short* xbfAO = (short*)(ws + 9ull * (1ull << 20));   // x_bf, later AO
    short* QKVc  = (short*)(ws + 25ull * (1ull << 20));

    detect_dtype<<<1, 256, 0, stream>>>((const unsigned short*)d_in[0], flag);

    if (ws_size < 73ull * 1048576) {
        fill_sentinel<<<(8388608 + 255) / 256, 256, 0, stream>>>(d_out, 8388608, flag);
        return;
    }

    conv_bias<<<12, 256, 0, stream>>>(d_in[2], bq_bf, 3072, flag);
    conv_bias<<<4, 256, 0, stream>>>(d_in[4], bo_bf, 1024, flag);
    transpose_poly<<<dim3(96, 32), 256, 0, stream>>>(d_in[1], WqkvT, 1024, 3072, flag);
    transpose_poly<<<dim3(32, 32), 256, 0, stream>>>(d_in[3], WoutT, 1024, 1024, flag);
    conv_x<<<8192, 256, 0, stream>>>(d_in[0], xbfAO, 8388608, flag);

    gemm_bt<<<dim3(24, 64), 256, 0, stream>>>(xbfAO, WqkvT, bq_bf, QKVc,
                                              3072, 1024, flag, 0, 8e4f);
    attn_kernel<<<dim3(8, 64), 256, 0, stream>>>(QKVc, xbfAO, (const int*)d_in[5]);
    gemm_bt<<<dim3(8, 64), 256, 0, stream>>>(xbfAO, WoutT, bo_bf, d_out,
                                             1024, 1024, flag, 1, 2e4f);
}